// Round 10
// baseline (252.908 us; speedup 1.0000x reference)
//
#include <hip/hip_runtime.h>
#include <hip/hip_bf16.h>
#include <stdint.h>

#define B_   4
#define C_   256
#define C8_  32
#define HW_  4096
#define ROWS_ 320   // 32 Q + 32 K + 256 V composite rows
#define MS_  4      // m-split factor
#define L2E  1.4426950408889634f

typedef __attribute__((ext_vector_type(8)))  short  short8;
typedef __attribute__((ext_vector_type(8)))  ushort us8;
typedef __attribute__((ext_vector_type(16))) float  f32x16;

// ---- workspace layout (bytes) ----
// All tensors FRAGMENT-MAJOR: 1KB frag = [64 lanes][8 ushort].
// Qf/Ktf: [b][blk32(128)][ks(2)]  lane=(q|m)&31 + 32*((e>>3)&1), j=e&7
// Vf:     [b][cblk(8)][mb(256)]   lane=c&31 + 32*((m>>3)&1),     j=m&7
// wbf:    [kc(16)][rowblk(10)]
#define WT_OFF    0
#define BALL_OFF  (256*320*4)
#define Q_OFF     (BALL_OFF + 1280)
#define KT_OFF    (Q_OFF  + B_*HW_*C8_*2)
#define V_OFF     (KT_OFF + B_*HW_*C8_*2)
#define PACC_OFF  (V_OFF  + B_*C_*HW_*2)
#define LPART_OFF (PACC_OFF + (size_t)MS_*B_*C_*HW_*2)
// total ~44.6 MB

__device__ __forceinline__ ushort f2bf(float f) {
    union { float f; uint32_t u; } v; v.f = f;
    uint32_t u = v.u;
    uint32_t r = u + 0x7fffu + ((u >> 16) & 1u);  // RNE
    return (ushort)(r >> 16);
}
__device__ __forceinline__ uint32_t pktr(float lo, float hi) {
    union { float f; uint32_t u; } a, b; a.f = lo; b.f = hi;
    return __builtin_amdgcn_perm(b.u, a.u, 0x07060302u);  // 1-instr trunc pack
}
// Schraudolph exp2: 3 VALU ops, +-3% centered rel error, 0 on underflow
__device__ __forceinline__ float fexp2(float s) {
    float y = fmaf(s, 8388608.0f, 1064992506.0f);   // (127-0.043)*2^23
    y = fmaxf(y, 0.0f);
    union { int i; float f; } c; c.i = (int)y;
    return c.f;
}

// ---------------- kernel 1: fold conv into weights (bf16, A-frag-major) ----
__global__ __launch_bounds__(256) void k_setup(
    const float* __restrict__ conv_w, const float* __restrict__ conv_b,
    const float* __restrict__ q_w, const float* __restrict__ q_b,
    const float* __restrict__ k_w, const float* __restrict__ k_b,
    const float* __restrict__ v_w, const float* __restrict__ v_b,
    ushort* __restrict__ wbf, float* __restrict__ ball)
{
    int r = blockIdx.x;        // 0..319 composite row
    int c = threadIdx.x;       // 0..255 input channel (k)
    const float* wrow;
    float bias;
    if (r < 32)       { wrow = q_w + r*32;      bias = q_b[r];      }
    else if (r < 64)  { wrow = k_w + (r-32)*32; bias = k_b[r-32];   }
    else              { wrow = v_w + (r-64)*32; bias = v_b[r-64];   }
    float acc = 0.f;
    #pragma unroll
    for (int d = 0; d < 32; ++d) acc += wrow[d] * conv_w[d*C_ + c];
    float scale = (r < 32) ? L2E : 1.0f;       // fold log2(e) into Q
    int lanew = (r & 31) + 32*((c >> 3) & 1);
    int fidx  = (c >> 4)*10 + (r >> 5);        // [kc][rowblk]
    wbf[fidx*512 + lanew*8 + (c & 7)] = f2bf(acc * scale);
    if (c == 0) {
        float bb = bias;
        #pragma unroll
        for (int d = 0; d < 32; ++d) bb += wrow[d] * conv_b[d];
        ball[r] = bb * scale;
    }
}

// ---------------- kernel 2: Q/Kt/V projection via MFMA + LDS transpose -----
// grid = B*128, 320 thr (5 waves = 320 rows x 32 n).
__global__ __launch_bounds__(320) void k_qkv(
    const float* __restrict__ x, const ushort* __restrict__ wbf,
    const float* __restrict__ ball,
    ushort* __restrict__ qg, ushort* __restrict__ ktg, ushort* __restrict__ vg)
{
    __shared__ ushort tr[5][32*40];   // per-wave 32x32 transpose tile, stride 40

    int blk = blockIdx.x;
    int b  = blk >> 7;
    int nt = blk & 127;                // n-tile index (32 cols)
    int n0 = nt * 32;
    int t = threadIdx.x;
    int w = t >> 6, lane = t & 63;
    int l31 = lane & 31, h = lane >> 5;

    f32x16 acc[2];
    acc[0] = (f32x16)(0.f);
    acc[1] = (f32x16)(0.f);

    const float* xb = x + (size_t)b*C_*HW_ + n0 + l31;

    #pragma unroll 2
    for (int kc = 0; kc < 16; ++kc) {          // K chunks of 16
        short8 a0 = *(const short8*)(wbf + (kc*10 + w*2    )*512 + lane*8);
        short8 a1 = *(const short8*)(wbf + (kc*10 + w*2 + 1)*512 + lane*8);
        const float* xc = xb + (size_t)(kc*16 + h*8)*HW_;
        union { uint32_t d[4]; short8 s8; } bf;
        #pragma unroll
        for (int j2 = 0; j2 < 4; ++j2) {
            float f0 = xc[(size_t)(2*j2    )*HW_];
            float f1 = xc[(size_t)(2*j2 + 1)*HW_];
            bf.d[j2] = pktr(f0, f1);
        }
        acc[0] = __builtin_amdgcn_mfma_f32_32x32x16_bf16(a0, bf.s8, acc[0], 0, 0, 0);
        acc[1] = __builtin_amdgcn_mfma_f32_32x32x16_bf16(a1, bf.s8, acc[1], 0, 0, 0);
    }

    // epilogue: per mi subtile, transpose in LDS, store contiguous frags
    #pragma unroll
    for (int mi = 0; mi < 2; ++mi) {
        int rowb = w*64 + mi*32;
        bool isQK = (rowb < 64);
        #pragma unroll
        for (int r = 0; r < 16; ++r) {
            int roff = (r & 3) + 8*(r >> 2) + 4*h;
            ushort bv = f2bf(acc[mi][r] + ball[rowb + roff]);
            int ad = isQK ? (l31*40 + roff) : (roff*40 + l31);
            tr[w][ad] = bv;
        }
        __syncthreads();
        #pragma unroll
        for (int f = 0; f < 2; ++f) {
            us8 frag = *(const us8*)(&tr[w][l31*40 + f*16 + h*8]);
            if (isQK) {
                ushort* dstb = (rowb == 0) ? qg : ktg;
                size_t ad = ((size_t)((b*128 + nt)*2 + f) << 9) + lane*8;
                *(us8*)(dstb + ad) = frag;
            } else {
                int cblk = (rowb - 64) >> 5;
                int mb = nt*2 + f;
                size_t ad = ((size_t)((b*8 + cblk)*256 + mb) << 9) + lane*8;
                *(us8*)(vg + ad) = frag;
            }
        }
        __syncthreads();
    }
}

// ---------------- kernel 3: flash attention, m-split partials ----------------
// grid = 512: ms=blk&3, cs=bit2, qb=bits[3:6] (stride-8 -> same-XCD sharing),
// b=bits[7:8]. 512 thr = 8 waves; wave = 32q x 128c, acc 64 AGPR, 4 waves/SIMD.
// MC=128 double-buffered (80KB LDS), 8 iters, 1 barrier/iter.
__global__ __launch_bounds__(512, 4) void k_attn(
    const ushort* __restrict__ qg, const ushort* __restrict__ ktg,
    const ushort* __restrict__ vg,
    ushort* __restrict__ pacc, float* __restrict__ lpart)
{
    __shared__ ushort v_lds[2][32*512];   // 32 V frags [cfr*8 + mf]
    __shared__ ushort kt_lds[2][8*512];   // 8 Kt frags [kb*2 + ks]

    int blk = blockIdx.x;
    int ms = blk & 3;
    int cs = (blk >> 2) & 1;
    int qb = (blk >> 3) & 15;
    int b  = blk >> 7;
    int t = threadIdx.x;
    int w = t >> 6, lane = t & 63;
    int l31 = lane & 31, h = lane >> 5;
    int mbase = ms*1024;

    // Q fragments: contiguous 1KB loads; wave w owns qblk = qb*8 + w
    short8 qf[2];
    #pragma unroll
    for (int ks = 0; ks < 2; ++ks)
        qf[ks] = *(const short8*)(qg
            + ((size_t)((b*128 + qb*8 + w)*2 + ks) << 9) + lane*8);

    f32x16 acc[4];
    #pragma unroll
    for (int j = 0; j < 4; ++j) acc[j] = (f32x16)(0.f);
    float lsum = 0.f;

    // staging per iter: wave w -> 4 V frags (f = w*4+ff) + 1 Kt frag (w)
    #define STAGE(buf, m0)                                                          \
    {                                                                               \
        _Pragma("unroll")                                                           \
        for (int ff = 0; ff < 4; ++ff) {                                            \
            int f = w*4 + ff;                                                       \
            int cfr = f >> 3, mf = f & 7;                                           \
            const ushort* src = vg + ((size_t)((b*8 + cs*4 + cfr)*256               \
                                 + ((m0) >> 4) + mf) << 9) + lane*8;                \
            __builtin_amdgcn_global_load_lds(                                       \
                (const __attribute__((address_space(1))) uint32_t*)src,             \
                (__attribute__((address_space(3))) uint32_t*)&v_lds[buf][f*512],    \
                16, 0, 0);                                                          \
        }                                                                           \
        {                                                                           \
            const ushort* src = ktg + ((size_t)((b*128 + ((m0) >> 5) + (w >> 1))*2  \
                                 + (w & 1)) << 9) + lane*8;                         \
            __builtin_amdgcn_global_load_lds(                                       \
                (const __attribute__((address_space(1))) uint32_t*)src,             \
                (__attribute__((address_space(3))) uint32_t*)&kt_lds[buf][w*512],   \
                16, 0, 0);                                                          \
        }                                                                           \
    }

    STAGE(0, mbase)
    __syncthreads();

    int buf = 0;
    for (int it = 0; it < 8; ++it) {
        if (it + 1 < 8) STAGE(buf ^ 1, mbase + (it+1)*128)

        #pragma unroll
        for (int kb = 0; kb < 4; ++kb) {
            short8 kt0 = *(const short8*)(&kt_lds[buf][(kb*2+0)*512 + lane*8]);
            short8 kt1 = *(const short8*)(&kt_lds[buf][(kb*2+1)*512 + lane*8]);

            // S (32k x 32q) -> fast exp2 -> truncated bf16 pairs
            f32x16 s = (f32x16)(0.f);
            s = __builtin_amdgcn_mfma_f32_32x32x16_bf16(kt0, qf[0], s, 0, 0, 0);
            s = __builtin_amdgcn_mfma_f32_32x32x16_bf16(kt1, qf[1], s, 0, 0, 0);
            float e[16];
            #pragma unroll
            for (int r = 0; r < 16; ++r) e[r] = fexp2(s[r]);
            float t0 = 0.f, t1 = 0.f;
            #pragma unroll
            for (int r = 0; r < 8; ++r) { t0 += e[2*r]; t1 += e[2*r+1]; }
            lsum += t0 + t1;
            uint32_t u[8];
            #pragma unroll
            for (int i = 0; i < 8; ++i) u[i] = pktr(e[2*i], e[2*i+1]);

            // PV B-fragments via lane-half exchange
            uint32_t bpA = (uint32_t)__shfl_xor((int)(h ? u[0] : u[2]), 32);
            uint32_t bpB = (uint32_t)__shfl_xor((int)(h ? u[1] : u[3]), 32);
            uint32_t bpC = (uint32_t)__shfl_xor((int)(h ? u[4] : u[6]), 32);
            uint32_t bpD = (uint32_t)__shfl_xor((int)(h ? u[5] : u[7]), 32);
            union { uint32_t d[4]; short8 s8; } fe, fo;
            fe.d[0] = h ? bpA : u[0];  fe.d[1] = h ? bpB : u[1];
            fe.d[2] = h ? u[2] : bpA;  fe.d[3] = h ? u[3] : bpB;
            fo.d[0] = h ? bpC : u[4];  fo.d[1] = h ? bpD : u[5];
            fo.d[2] = h ? u[6] : bpC;  fo.d[3] = h ? u[7] : bpD;
            short8 pf0 = fe.s8;   // keys kb*32 + [0,16)
            short8 pf1 = fo.s8;   // keys kb*32 + [16,32)

            #pragma unroll
            for (int msub = 0; msub < 2; ++msub) {
                int ks16 = kb*2 + msub;
                short8 pfm = msub ? pf1 : pf0;
                #pragma unroll
                for (int cfr = 0; cfr < 4; ++cfr) {
                    short8 vf = *(const short8*)(&v_lds[buf][(cfr*8 + ks16)*512 + lane*8]);
                    acc[cfr] = __builtin_amdgcn_mfma_f32_32x32x16_bf16(vf, pfm, acc[cfr], 0, 0, 0);
                }
            }
        }
        __syncthreads();
        buf ^= 1;
    }

    // finalize l: add other lane-half's key contributions
    {
        union { float f; int i; } cv; cv.f = lsum;
        cv.i = __shfl_xor(cv.i, 32);
        lsum += cv.f;
    }
    if (cs == 0 && h == 0)
        lpart[(size_t)(ms*B_ + b)*HW_ + qb*256 + w*32 + l31] = lsum;

    // pacc raw fragment dump: contiguous 2KB per cfr wave-store
    int blkl = ((ms*B_ + b)*16 + qb)*2 + cs;
    #pragma unroll
    for (int cfr = 0; cfr < 4; ++cfr) {
        union { uint32_t d[8]; us8 hlf[2]; } pk;
        #pragma unroll
        for (int i = 0; i < 8; ++i)
            pk.d[i] = pktr(acc[cfr][2*i], acc[cfr][2*i+1]);
        ushort* dst = pacc + ((size_t)(blkl*32 + w*4 + cfr) << 10);
        *(us8*)(dst + lane*8)       = pk.hlf[0];
        *(us8*)(dst + 512 + lane*8) = pk.hlf[1];
    }
    #undef STAGE
}

// ---------------- kernel 4: combine via LDS transpose + epilogue ----------
// grid = 1024 blocks (b,qb,cs,w), 256 thr. Phase 1: frag-native decode +
// gamma/l fold -> LDS [128c][36]. Phase 2: float4 x/out (8 full lines/instr).
__global__ __launch_bounds__(256) void k_comb(
    const ushort* __restrict__ pacc, const float* __restrict__ lpart,
    const float* __restrict__ x, const float* __restrict__ gamma_p,
    float* __restrict__ out)
{
    __shared__ float lds_acc[128*36];   // 18.4 KB

    int blk = blockIdx.x;
    int w  = blk & 7;
    int cs = (blk >> 3) & 1;
    int qb = (blk >> 4) & 15;
    int b  = blk >> 8;
    int t = threadIdx.x;

    // phase 1: t -> (l31 q, h, cfr)
    int l31 = t & 31;
    int h   = (t >> 5) & 1;
    int cfr = (t >> 6) & 3;
    int q = qb*256 + w*32 + l31;
    int lanef = h*32 + l31;

    float sum[16];
    #pragma unroll
    for (int k = 0; k < 16; ++k) sum[k] = 0.f;
    float lt = 0.f;

    #pragma unroll
    for (int ms = 0; ms < MS_; ++ms) {
        int blkl = ((ms*B_ + b)*16 + qb)*2 + cs;
        const ushort* pp = pacc + ((size_t)(blkl*32 + w*4 + cfr) << 10) + lanef*8;
        us8 a0 = *(const us8*)pp;
        us8 a1 = *(const us8*)(pp + 512);
        #pragma unroll
        for (int k = 0; k < 8; ++k) {
            union { uint32_t u; float f; } cv;
            cv.u = ((uint32_t)a0[k]) << 16;  sum[k]   += cv.f;
            cv.u = ((uint32_t)a1[k]) << 16;  sum[k+8] += cv.f;
        }
        lt += lpart[(size_t)(ms*B_ + b)*HW_ + q];
    }

    float rl = gamma_p[0] / lt;
    #pragma unroll
    for (int k = 0; k < 16; ++k) {
        int c = cfr*32 + (k & 3) + 8*(k >> 2) + 4*h;
        lds_acc[c*36 + l31] = sum[k]*rl;
    }
    __syncthreads();

    // phase 2: 1024 float4 slots [c(128)][qg(8)]; thread does 4 slots
    const float* xb = x + ((size_t)(b*C_ + cs*128))*HW_ + qb*256 + w*32;
    float* ob = out + ((size_t)(b*C_ + cs*128))*HW_ + qb*256 + w*32;
    #pragma unroll
    for (int i = 0; i < 4; ++i) {
        int s = t + i*256;
        int c = s >> 3, qg = s & 7;
        float4 a = *(const float4*)(&lds_acc[c*36 + qg*4]);
        size_t off = (size_t)c*HW_ + qg*4;
        float4 xv = *(const float4*)(xb + off);
        a.x += xv.x; a.y += xv.y; a.z += xv.z; a.w += xv.w;
        *(float4*)(ob + off) = a;
    }
}

extern "C" void kernel_launch(void* const* d_in, const int* in_sizes, int n_in,
                              void* d_out, int out_size, void* d_ws, size_t ws_size,
                              hipStream_t stream)
{
    const float* x      = (const float*)d_in[0];
    const float* conv_w = (const float*)d_in[1];
    const float* conv_b = (const float*)d_in[2];
    const float* q_w    = (const float*)d_in[3];
    const float* q_b    = (const float*)d_in[4];
    const float* k_w    = (const float*)d_in[5];
    const float* k_b    = (const float*)d_in[6];
    const float* v_w    = (const float*)d_in[7];
    const float* v_b    = (const float*)d_in[8];
    const float* gamma  = (const float*)d_in[9];
    float* out = (float*)d_out;

    char* ws = (char*)d_ws;
    ushort* wbf   = (ushort*)(ws + WT_OFF);
    float*  ball  = (float*)(ws + BALL_OFF);
    ushort* qg    = (ushort*)(ws + Q_OFF);
    ushort* ktg   = (ushort*)(ws + KT_OFF);
    ushort* vg    = (ushort*)(ws + V_OFF);
    ushort* pacc  = (ushort*)(ws + PACC_OFF);
    float*  lpart = (float*)(ws + LPART_OFF);

    k_setup<<<ROWS_, 256, 0, stream>>>(conv_w, conv_b, q_w, q_b, k_w, k_b,
                                       v_w, v_b, wbf, ball);
    k_qkv<<<B_*128, 320, 0, stream>>>(x, wbf, ball, qg, ktg, vg);
    k_attn<<<512, 512, 0, stream>>>(qg, ktg, vg, pacc, lpart);
    k_comb<<<1024, 256, 0, stream>>>(pacc, lpart, x, gamma, out);
}

// Round 11
// 154.556 us; speedup vs baseline: 1.6364x; 1.6364x over previous
//
#include <hip/hip_runtime.h>
#include <hip/hip_bf16.h>
#include <stdint.h>

#define B_   4
#define C_   256
#define C8_  32
#define HW_  4096
#define ROWS_ 320   // 32 Q + 32 K + 256 V composite rows
#define MS_  4      // m-split factor
#define L2E  1.4426950408889634f

typedef __attribute__((ext_vector_type(8)))  short  short8;
typedef __attribute__((ext_vector_type(8)))  ushort us8;
typedef __attribute__((ext_vector_type(2)))  float  f32x2;
typedef __attribute__((ext_vector_type(16))) float  f32x16;

// ---- workspace layout (bytes) ----
// All tensors FRAGMENT-MAJOR: 1KB frag = [64 lanes][8 ushort].
// Qf/Ktf: [b][blk32(128)][ks(2)]  lane=(q|m)&31 + 32*((e>>3)&1), j=e&7
// Vf:     [b][cblk(8)][mb(256)]   lane=c&31 + 32*((m>>3)&1),     j=m&7
// wbf:    [kc(16)][rowblk(10)]
#define WT_OFF    0
#define BALL_OFF  (256*320*4)
#define Q_OFF     (BALL_OFF + 1280)
#define KT_OFF    (Q_OFF  + B_*HW_*C8_*2)
#define V_OFF     (KT_OFF + B_*HW_*C8_*2)
#define PACC_OFF  (V_OFF  + B_*C_*HW_*2)
#define LPART_OFF (PACC_OFF + (size_t)MS_*B_*C_*HW_*2)
// total ~44.6 MB

__device__ __forceinline__ ushort f2bf(float f) {
    union { float f; uint32_t u; } v; v.f = f;
    uint32_t u = v.u;
    uint32_t r = u + 0x7fffu + ((u >> 16) & 1u);  // RNE
    return (ushort)(r >> 16);
}
__device__ __forceinline__ uint32_t pktr(float lo, float hi) {
    union { float f; uint32_t u; } a, b; a.f = lo; b.f = hi;
    return __builtin_amdgcn_perm(b.u, a.u, 0x07060302u);  // 1-instr trunc pack
}
// Packed Schraudolph exp2 on a pair: v_pk_fma + v_pk_max + 2 cvt + 1 perm.
// Returns packed bf16 pair; e01 gets the two fp32 values for the l-sum.
__device__ __forceinline__ uint32_t fexp2_pk(float s0, float s1, f32x2& e01) {
    f32x2 s = {s0, s1};
    f32x2 y = __builtin_elementwise_fma(s, (f32x2)(8388608.0f),
                                        (f32x2)(1064992506.0f)); // (127-0.043)*2^23
    y = __builtin_elementwise_max(y, (f32x2)(0.0f));
    union { int i; float f; } c0, c1;
    c0.i = (int)y.x;  c1.i = (int)y.y;
    e01.x = c0.f;  e01.y = c1.f;
    return __builtin_amdgcn_perm((uint32_t)c1.i, (uint32_t)c0.i, 0x07060302u);
}

// ---------------- kernel 1: fold conv into weights (bf16, A-frag-major) ----
__global__ __launch_bounds__(256) void k_setup(
    const float* __restrict__ conv_w, const float* __restrict__ conv_b,
    const float* __restrict__ q_w, const float* __restrict__ q_b,
    const float* __restrict__ k_w, const float* __restrict__ k_b,
    const float* __restrict__ v_w, const float* __restrict__ v_b,
    ushort* __restrict__ wbf, float* __restrict__ ball)
{
    int r = blockIdx.x;        // 0..319 composite row
    int c = threadIdx.x;       // 0..255 input channel (k)
    const float* wrow;
    float bias;
    if (r < 32)       { wrow = q_w + r*32;      bias = q_b[r];      }
    else if (r < 64)  { wrow = k_w + (r-32)*32; bias = k_b[r-32];   }
    else              { wrow = v_w + (r-64)*32; bias = v_b[r-64];   }
    float acc = 0.f;
    #pragma unroll
    for (int d = 0; d < 32; ++d) acc += wrow[d] * conv_w[d*C_ + c];
    float scale = (r < 32) ? L2E : 1.0f;       // fold log2(e) into Q
    int lanew = (r & 31) + 32*((c >> 3) & 1);
    int fidx  = (c >> 4)*10 + (r >> 5);        // [kc][rowblk]
    wbf[fidx*512 + lanew*8 + (c & 7)] = f2bf(acc * scale);
    if (c == 0) {
        float bb = bias;
        #pragma unroll
        for (int d = 0; d < 32; ++d) bb += wrow[d] * conv_b[d];
        ball[r] = bb * scale;
    }
}

// ---------------- kernel 2: Q/Kt/V projection via MFMA + LDS transpose -----
// grid = B*128, 320 thr (5 waves = 320 rows x 32 n).
__global__ __launch_bounds__(320) void k_qkv(
    const float* __restrict__ x, const ushort* __restrict__ wbf,
    const float* __restrict__ ball,
    ushort* __restrict__ qg, ushort* __restrict__ ktg, ushort* __restrict__ vg)
{
    __shared__ ushort tr[5][32*40];   // per-wave 32x32 transpose tile, stride 40

    int blk = blockIdx.x;
    int b  = blk >> 7;
    int nt = blk & 127;                // n-tile index (32 cols)
    int n0 = nt * 32;
    int t = threadIdx.x;
    int w = t >> 6, lane = t & 63;
    int l31 = lane & 31, h = lane >> 5;

    f32x16 acc[2];
    acc[0] = (f32x16)(0.f);
    acc[1] = (f32x16)(0.f);

    const float* xb = x + (size_t)b*C_*HW_ + n0 + l31;

    #pragma unroll 2
    for (int kc = 0; kc < 16; ++kc) {          // K chunks of 16
        short8 a0 = *(const short8*)(wbf + (kc*10 + w*2    )*512 + lane*8);
        short8 a1 = *(const short8*)(wbf + (kc*10 + w*2 + 1)*512 + lane*8);
        const float* xc = xb + (size_t)(kc*16 + h*8)*HW_;
        union { uint32_t d[4]; short8 s8; } bf;
        #pragma unroll
        for (int j2 = 0; j2 < 4; ++j2) {
            float f0 = xc[(size_t)(2*j2    )*HW_];
            float f1 = xc[(size_t)(2*j2 + 1)*HW_];
            bf.d[j2] = pktr(f0, f1);
        }
        acc[0] = __builtin_amdgcn_mfma_f32_32x32x16_bf16(a0, bf.s8, acc[0], 0, 0, 0);
        acc[1] = __builtin_amdgcn_mfma_f32_32x32x16_bf16(a1, bf.s8, acc[1], 0, 0, 0);
    }

    // epilogue: per mi subtile, transpose in LDS, store contiguous frags
    #pragma unroll
    for (int mi = 0; mi < 2; ++mi) {
        int rowb = w*64 + mi*32;
        bool isQK = (rowb < 64);
        #pragma unroll
        for (int r = 0; r < 16; ++r) {
            int roff = (r & 3) + 8*(r >> 2) + 4*h;
            ushort bv = f2bf(acc[mi][r] + ball[rowb + roff]);
            int ad = isQK ? (l31*40 + roff) : (roff*40 + l31);
            tr[w][ad] = bv;
        }
        __syncthreads();
        #pragma unroll
        for (int f = 0; f < 2; ++f) {
            us8 frag = *(const us8*)(&tr[w][l31*40 + f*16 + h*8]);
            if (isQK) {
                ushort* dstb = (rowb == 0) ? qg : ktg;
                size_t ad = ((size_t)((b*128 + nt)*2 + f) << 9) + lane*8;
                *(us8*)(dstb + ad) = frag;
            } else {
                int cblk = (rowb - 64) >> 5;
                int mb = nt*2 + f;
                size_t ad = ((size_t)((b*8 + cblk)*256 + mb) << 9) + lane*8;
                *(us8*)(vg + ad) = frag;
            }
        }
        __syncthreads();
    }
}

// ---------------- kernel 3: flash attention, m-split partials ----------------
// grid = 512: ms=blk&3, cs=bit2, qb=bits[3:6] (stride-8 -> same-XCD sharing),
// b=bits[7:8]. 512 thr = 8 waves; wave = 32q x 128c, acc 64 AGPR, 4 waves/SIMD.
// MC=64 double-buffered (40KB LDS) -- MC=128 spills (R8/R10: SGPR 112, 685MB).
__global__ __launch_bounds__(512, 4) void k_attn(
    const ushort* __restrict__ qg, const ushort* __restrict__ ktg,
    const ushort* __restrict__ vg,
    ushort* __restrict__ pacc, float* __restrict__ lpart)
{
    __shared__ ushort v_lds[2][16*512];   // 16 V frags [cfr*4 + mf]
    __shared__ ushort kt_lds[2][4*512];   // 4 Kt frags [kb*2 + ks]

    int blk = blockIdx.x;
    int ms = blk & 3;
    int cs = (blk >> 2) & 1;
    int qb = (blk >> 3) & 15;
    int b  = blk >> 7;
    int t = threadIdx.x;
    int w = t >> 6, lane = t & 63;
    int l31 = lane & 31, h = lane >> 5;
    int mbase = ms*1024;

    // Q fragments: contiguous 1KB loads; wave w owns qblk = qb*8 + w
    short8 qf[2];
    #pragma unroll
    for (int ks = 0; ks < 2; ++ks)
        qf[ks] = *(const short8*)(qg
            + ((size_t)((b*128 + qb*8 + w)*2 + ks) << 9) + lane*8);

    f32x16 acc[4];
    #pragma unroll
    for (int j = 0; j < 4; ++j) acc[j] = (f32x16)(0.f);
    f32x2 lacc = {0.f, 0.f};

    // staging: V 16 frags -> 2/wave ; Kt 4 frags -> waves 0..3
    #define STAGE(buf, m0)                                                          \
    {                                                                               \
        _Pragma("unroll")                                                           \
        for (int ff = 0; ff < 2; ++ff) {                                            \
            int f = w*2 + ff;                                                       \
            int cfr = f >> 2, mf = f & 3;                                           \
            const ushort* src = vg + ((size_t)((b*8 + cs*4 + cfr)*256               \
                                 + ((m0) >> 4) + mf) << 9) + lane*8;                \
            __builtin_amdgcn_global_load_lds(                                       \
                (const __attribute__((address_space(1))) uint32_t*)src,             \
                (__attribute__((address_space(3))) uint32_t*)&v_lds[buf][f*512],    \
                16, 0, 0);                                                          \
        }                                                                           \
        if (w < 4) {                                                                \
            const ushort* src = ktg + ((size_t)((b*128 + ((m0) >> 5) + (w >> 1))*2  \
                                 + (w & 1)) << 9) + lane*8;                         \
            __builtin_amdgcn_global_load_lds(                                       \
                (const __attribute__((address_space(1))) uint32_t*)src,             \
                (__attribute__((address_space(3))) uint32_t*)&kt_lds[buf][w*512],   \
                16, 0, 0);                                                          \
        }                                                                           \
    }

    STAGE(0, mbase)
    __syncthreads();

    int buf = 0;
    for (int it = 0; it < 16; ++it) {
        if (it + 1 < 16) STAGE(buf ^ 1, mbase + (it+1)*64)

        #pragma unroll
        for (int kb = 0; kb < 2; ++kb) {
            short8 kt0 = *(const short8*)(&kt_lds[buf][(kb*2+0)*512 + lane*8]);
            short8 kt1 = *(const short8*)(&kt_lds[buf][(kb*2+1)*512 + lane*8]);

            // S (32k x 32q) -> packed Schraudolph exp2 -> bf16 pairs
            f32x16 s = (f32x16)(0.f);
            s = __builtin_amdgcn_mfma_f32_32x32x16_bf16(kt0, qf[0], s, 0, 0, 0);
            s = __builtin_amdgcn_mfma_f32_32x32x16_bf16(kt1, qf[1], s, 0, 0, 0);
            uint32_t u[8];
            #pragma unroll
            for (int i = 0; i < 8; ++i) {
                f32x2 e01;
                u[i] = fexp2_pk(s[2*i], s[2*i+1], e01);
                lacc += e01;
            }

            // PV B-fragments via lane-half exchange
            uint32_t bpA = (uint32_t)__shfl_xor((int)(h ? u[0] : u[2]), 32);
            uint32_t bpB = (uint32_t)__shfl_xor((int)(h ? u[1] : u[3]), 32);
            uint32_t bpC = (uint32_t)__shfl_xor((int)(h ? u[4] : u[6]), 32);
            uint32_t bpD = (uint32_t)__shfl_xor((int)(h ? u[5] : u[7]), 32);
            union { uint32_t d[4]; short8 s8; } fe, fo;
            fe.d[0] = h ? bpA : u[0];  fe.d[1] = h ? bpB : u[1];
            fe.d[2] = h ? u[2] : bpA;  fe.d[3] = h ? u[3] : bpB;
            fo.d[0] = h ? bpC : u[4];  fo.d[1] = h ? bpD : u[5];
            fo.d[2] = h ? u[6] : bpC;  fo.d[3] = h ? u[7] : bpD;
            short8 pf0 = fe.s8;   // keys kb*32 + [0,16)
            short8 pf1 = fo.s8;   // keys kb*32 + [16,32)

            #pragma unroll
            for (int msub = 0; msub < 2; ++msub) {
                int ks16 = kb*2 + msub;
                short8 pfm = msub ? pf1 : pf0;
                #pragma unroll
                for (int cfr = 0; cfr < 4; ++cfr) {
                    short8 vf = *(const short8*)(&v_lds[buf][(cfr*4 + ks16)*512 + lane*8]);
                    acc[cfr] = __builtin_amdgcn_mfma_f32_32x32x16_bf16(vf, pfm, acc[cfr], 0, 0, 0);
                }
            }
        }
        __syncthreads();
        buf ^= 1;
    }

    // finalize l: horizontal + other lane-half's key contributions
    float lsum = lacc.x + lacc.y;
    {
        union { float f; int i; } cv; cv.f = lsum;
        cv.i = __shfl_xor(cv.i, 32);
        lsum += cv.f;
    }
    if (cs == 0 && h == 0)
        lpart[(size_t)(ms*B_ + b)*HW_ + qb*256 + w*32 + l31] = lsum;

    // pacc raw fragment dump: contiguous 2KB per cfr wave-store
    int blkl = ((ms*B_ + b)*16 + qb)*2 + cs;
    #pragma unroll
    for (int cfr = 0; cfr < 4; ++cfr) {
        union { uint32_t d[8]; us8 hlf[2]; } pk;
        #pragma unroll
        for (int i = 0; i < 8; ++i)
            pk.d[i] = pktr(acc[cfr][2*i], acc[cfr][2*i+1]);
        ushort* dst = pacc + ((size_t)(blkl*32 + w*4 + cfr) << 10);
        *(us8*)(dst + lane*8)       = pk.hlf[0];
        *(us8*)(dst + 512 + lane*8) = pk.hlf[1];
    }
    #undef STAGE
}

// ---------------- kernel 4: combine via LDS transpose + epilogue ----------
// grid = 1024 blocks (b,qb,cs,w), 256 thr. Phase 1: frag-native decode +
// gamma/l fold -> LDS [128c][36]. Phase 2: float4 x/out (full lines).
__global__ __launch_bounds__(256) void k_comb(
    const ushort* __restrict__ pacc, const float* __restrict__ lpart,
    const float* __restrict__ x, const float* __restrict__ gamma_p,
    float* __restrict__ out)
{
    __shared__ float lds_acc[128*36];   // 18.4 KB

    int blk = blockIdx.x;
    int w  = blk & 7;
    int cs = (blk >> 3) & 1;
    int qb = (blk >> 4) & 15;
    int b  = blk >> 8;
    int t = threadIdx.x;

    int l31 = t & 31;
    int h   = (t >> 5) & 1;
    int cfr = (t >> 6) & 3;
    int q = qb*256 + w*32 + l31;
    int lanef = h*32 + l31;

    float sum[16];
    #pragma unroll
    for (int k = 0; k < 16; ++k) sum[k] = 0.f;
    float lt = 0.f;

    #pragma unroll
    for (int ms = 0; ms < MS_; ++ms) {
        int blkl = ((ms*B_ + b)*16 + qb)*2 + cs;
        const ushort* pp = pacc + ((size_t)(blkl*32 + w*4 + cfr) << 10) + lanef*8;
        us8 a0 = *(const us8*)pp;
        us8 a1 = *(const us8*)(pp + 512);
        #pragma unroll
        for (int k = 0; k < 8; ++k) {
            union { uint32_t u; float f; } cv;
            cv.u = ((uint32_t)a0[k]) << 16;  sum[k]   += cv.f;
            cv.u = ((uint32_t)a1[k]) << 16;  sum[k+8] += cv.f;
        }
        lt += lpart[(size_t)(ms*B_ + b)*HW_ + q];
    }

    float rl = gamma_p[0] / lt;
    #pragma unroll
    for (int k = 0; k < 16; ++k) {
        int c = cfr*32 + (k & 3) + 8*(k >> 2) + 4*h;
        lds_acc[c*36 + l31] = sum[k]*rl;
    }
    __syncthreads();

    // phase 2: 1024 float4 slots [c(128)][qg(8)]; thread does 4 slots
    const float* xb = x + ((size_t)(b*C_ + cs*128))*HW_ + qb*256 + w*32;
    float* ob = out + ((size_t)(b*C_ + cs*128))*HW_ + qb*256 + w*32;
    #pragma unroll
    for (int i = 0; i < 4; ++i) {
        int s = t + i*256;
        int c = s >> 3, qg = s & 7;
        float4 a = *(const float4*)(&lds_acc[c*36 + qg*4]);
        size_t off = (size_t)c*HW_ + qg*4;
        float4 xv = *(const float4*)(xb + off);
        a.x += xv.x; a.y += xv.y; a.z += xv.z; a.w += xv.w;
        *(float4*)(ob + off) = a;
    }
}

extern "C" void kernel_launch(void* const* d_in, const int* in_sizes, int n_in,
                              void* d_out, int out_size, void* d_ws, size_t ws_size,
                              hipStream_t stream)
{
    const float* x      = (const float*)d_in[0];
    const float* conv_w = (const float*)d_in[1];
    const float* conv_b = (const float*)d_in[2];
    const float* q_w    = (const float*)d_in[3];
    const float* q_b    = (const float*)d_in[4];
    const float* k_w    = (const float*)d_in[5];
    const float* k_b    = (const float*)d_in[6];
    const float* v_w    = (const float*)d_in[7];
    const float* v_b    = (const float*)d_in[8];
    const float* gamma  = (const float*)d_in[9];
    float* out = (float*)d_out;

    char* ws = (char*)d_ws;
    ushort* wbf   = (ushort*)(ws + WT_OFF);
    float*  ball  = (float*)(ws + BALL_OFF);
    ushort* qg    = (ushort*)(ws + Q_OFF);
    ushort* ktg   = (ushort*)(ws + KT_OFF);
    ushort* vg    = (ushort*)(ws + V_OFF);
    ushort* pacc  = (ushort*)(ws + PACC_OFF);
    float*  lpart = (float*)(ws + LPART_OFF);

    k_setup<<<ROWS_, 256, 0, stream>>>(conv_w, conv_b, q_w, q_b, k_w, k_b,
                                       v_w, v_b, wbf, ball);
    k_qkv<<<B_*128, 320, 0, stream>>>(x, wbf, ball, qg, ktg, vg);
    k_attn<<<512, 512, 0, stream>>>(qg, ktg, vg, pacc, lpart);
    k_comb<<<1024, 256, 0, stream>>>(pacc, lpart, x, gamma, out);
}